// Round 1
// baseline (1867.366 us; speedup 1.0000x reference)
//
#include <hip/hip_runtime.h>
#include <hip/hip_bf16.h>

#define NB 2
#define NN 50000
#define NKK 16
#define ND 64
#define TB 256

static constexpr float EPS = 1e-5f;

__device__ __forceinline__ float b2f(__hip_bfloat16 h) { return __bfloat162float(h); }
__device__ __forceinline__ __hip_bfloat16 f2b(float f) { return __float2bfloat16(f); }

template <int DIM>
__device__ __forceinline__ void ln_lrelu(float* acc, const float* __restrict__ ls,
                                         const float* __restrict__ lb) {
  float s = 0.f;
#pragma unroll
  for (int c = 0; c < DIM; ++c) s += acc[c];
  const float m = s * (1.0f / DIM);
  float vs = 0.f;
#pragma unroll
  for (int c = 0; c < DIM; ++c) { float d = acc[c] - m; vs += d * d; }
  const float inv = rsqrtf(vs * (1.0f / DIM) + EPS);
#pragma unroll
  for (int c = 0; c < DIM; ++c) {
    float y = (acc[c] - m) * inv * ls[c] + lb[c];
    acc[c] = (y >= 0.f) ? y : 0.2f * y;
  }
}

// acc[OUT] = bias + sum_i h[i] * W[i][:]   (h from LDS, runtime i; W uniform -> s_load)
template <int IN, int OUT>
__device__ __forceinline__ void layer(const __hip_bfloat16* __restrict__ hbuf, int t,
                                      const float* __restrict__ w,
                                      const float* __restrict__ bias, float* acc) {
#pragma unroll
  for (int c = 0; c < OUT; ++c) acc[c] = bias[c];
  for (int i = 0; i < IN; ++i) {
    const float hi = b2f(hbuf[i * TB + t]);
    const float* wr = w + i * OUT;
#pragma unroll
    for (int c = 0; c < OUT; ++c) acc[c] += hi * wr[c];
  }
}

template <int DIM>
__device__ __forceinline__ void store_h(__hip_bfloat16* hbuf, int t, int base,
                                        const float* acc) {
#pragma unroll
  for (int c = 0; c < DIM; ++c) hbuf[(base + c) * TB + t] = f2b(acc[c]);
}

extern "C" __global__ void __launch_bounds__(TB)
lfa_fused(const float* __restrict__ pf, const float* __restrict__ geom,
          const int* __restrict__ nidx,
          const float* __restrict__ g_w1, const float* __restrict__ g_b1,
          const float* __restrict__ g_ls1, const float* __restrict__ g_lb1,
          const float* __restrict__ g_w2, const float* __restrict__ g_b2,
          const float* __restrict__ g_ls2, const float* __restrict__ g_lb2,
          const float* __restrict__ g_w3, const float* __restrict__ g_b3,
          const float* __restrict__ f_w1, const float* __restrict__ f_b1,
          const float* __restrict__ f_ls1, const float* __restrict__ f_lb1,
          const float* __restrict__ f_w2, const float* __restrict__ f_b2,
          const float* __restrict__ f_ls2, const float* __restrict__ f_lb2,
          const float* __restrict__ f_w3, const float* __restrict__ f_b3,
          float* __restrict__ out) {
  extern __shared__ __hip_bfloat16 hbuf[];  // [128][TB] = 64 KB
  const int t = threadIdx.x;
  const int r = blockIdx.x * TB + t;  // row id in [0, B*N*K), exact grid
  const int b = r / (NN * NKK);
  const int n = (r / NKK) % NN;
  const int kk = t & 15;

  float acc[128];

  // ---- geom MLP layer 1: 4 -> 64 (geom input stays in registers) ----
  const float4 g4 = *reinterpret_cast<const float4*>(geom + (size_t)r * 4);
  const float gin[4] = {g4.x, g4.y, g4.z, g4.w};
#pragma unroll
  for (int c = 0; c < 64; ++c) acc[c] = g_b1[c];
#pragma unroll
  for (int i = 0; i < 4; ++i) {
    const float* wr = g_w1 + i * 64;
#pragma unroll
    for (int c = 0; c < 64; ++c) acc[c] += gin[i] * wr[c];
  }
  ln_lrelu<64>(acc, g_ls1, g_lb1);
  store_h<64>(hbuf, t, 0, acc);

  // ---- geom layer 2: 64 -> 128 ----
  layer<64, 128>(hbuf, t, g_w2, g_b2, acc);
  ln_lrelu<128>(acc, g_ls2, g_lb2);
  store_h<128>(hbuf, t, 0, acc);

  // ---- geom layer 3: 128 -> 64 (no LN/act) ----
  layer<128, 64>(hbuf, t, g_w3, g_b3, acc);
  store_h<64>(hbuf, t, 0, acc);

  // ---- gather neighbor point features into hbuf[64..127] ----
  const int nb = nidx[r];
  const float4* prow =
      reinterpret_cast<const float4*>(pf + ((size_t)b * NN + nb) * ND);
#pragma unroll
  for (int q = 0; q < 16; ++q) {
    const float4 p4 = prow[q];
    hbuf[(64 + q * 4 + 0) * TB + t] = f2b(p4.x);
    hbuf[(64 + q * 4 + 1) * TB + t] = f2b(p4.y);
    hbuf[(64 + q * 4 + 2) * TB + t] = f2b(p4.z);
    hbuf[(64 + q * 4 + 3) * TB + t] = f2b(p4.w);
  }

  // ---- feature MLP layer 1: 128 -> 64 ----
  layer<128, 64>(hbuf, t, f_w1, f_b1, acc);
  ln_lrelu<64>(acc, f_ls1, f_lb1);
  store_h<64>(hbuf, t, 0, acc);

  // ---- feature MLP layer 2: 64 -> 128 ----
  layer<64, 128>(hbuf, t, f_w2, f_b2, acc);
  ln_lrelu<128>(acc, f_ls2, f_lb2);

  // ---- mean over K=16 (affine final layer commutes with mean) ----
#pragma unroll
  for (int c = 0; c < 128; ++c) {
    float v = acc[c];
    v += __shfl_xor(v, 1);
    v += __shfl_xor(v, 2);
    v += __shfl_xor(v, 4);
    v += __shfl_xor(v, 8);
    acc[c] = v * (1.0f / 16.0f);
  }

  // ---- final layer 128 -> 64, 4 output channels per lane of the 16-group ----
  const float4 b4 = *reinterpret_cast<const float4*>(f_b3 + kk * 4);
  float o0 = b4.x, o1 = b4.y, o2 = b4.z, o3 = b4.w;
#pragma unroll
  for (int i = 0; i < 128; ++i) {
    const float4 w4 =
        *reinterpret_cast<const float4*>(f_w3 + i * 64 + kk * 4);
    o0 += acc[i] * w4.x;
    o1 += acc[i] * w4.y;
    o2 += acc[i] * w4.z;
    o3 += acc[i] * w4.w;
  }
  const float4 o4 = make_float4(o0, o1, o2, o3);
  *reinterpret_cast<float4*>(out + ((size_t)b * NN + n) * ND + kk * 4) = o4;
}

extern "C" void kernel_launch(void* const* d_in, const int* in_sizes, int n_in,
                              void* d_out, int out_size, void* d_ws, size_t ws_size,
                              hipStream_t stream) {
  const float* pf = (const float*)d_in[0];
  const float* geom = (const float*)d_in[1];
  const int* nidx = (const int*)d_in[2];
  const float* g_w1 = (const float*)d_in[3];
  const float* g_b1 = (const float*)d_in[4];
  const float* g_ls1 = (const float*)d_in[5];
  const float* g_lb1 = (const float*)d_in[6];
  const float* g_w2 = (const float*)d_in[7];
  const float* g_b2 = (const float*)d_in[8];
  const float* g_ls2 = (const float*)d_in[9];
  const float* g_lb2 = (const float*)d_in[10];
  const float* g_w3 = (const float*)d_in[11];
  const float* g_b3 = (const float*)d_in[12];
  const float* f_w1 = (const float*)d_in[13];
  const float* f_b1 = (const float*)d_in[14];
  const float* f_ls1 = (const float*)d_in[15];
  const float* f_lb1 = (const float*)d_in[16];
  const float* f_w2 = (const float*)d_in[17];
  const float* f_b2 = (const float*)d_in[18];
  const float* f_ls2 = (const float*)d_in[19];
  const float* f_lb2 = (const float*)d_in[20];
  const float* f_w3 = (const float*)d_in[21];
  const float* f_b3 = (const float*)d_in[22];

  const int rows = NB * NN * NKK;      // 1,600,000
  const int grid = rows / TB;          // 6250 (exact)
  lfa_fused<<<grid, TB, 128 * TB * (int)sizeof(__hip_bfloat16), stream>>>(
      pf, geom, nidx, g_w1, g_b1, g_ls1, g_lb1, g_w2, g_b2, g_ls2, g_lb2, g_w3,
      g_b3, f_w1, f_b1, f_ls1, f_lb1, f_w2, f_b2, f_ls2, f_lb2, f_w3, f_b3,
      (float*)d_out);
}